// Round 10
// baseline (365.457 us; speedup 1.0000x reference)
//
#include <hip/hip_runtime.h>
#include <hip/hip_bf16.h>
#include <cstdint>

// ParaNet_Point round-10: 8-wave shared-A conv blocks.
// r9 lesson: Cout-split duplicated the A-build -> VALUBusy 66%, conv3 regressed.
// Now: 512 threads, 8 waves (2M x 4N), Cout unsplit. The 8 (channel,g-quarter)
// A-build tasks map 1:1 onto waves (wave-uniform channel select) -> per-thread
// A-build halves AND is built once for all Cout. acc stays 32 AGPR/wave.
// conv3: LDS 49.7KB, target 2 blocks x 8 waves = 50% occupancy.
// Numerics bit-identical to r9 -> absmax must remain exactly 0.0078125.

#define GRIDW 256
#define NPTS  65536
#define RADI  0.0125f
#define EPSF  1e-12f

typedef unsigned short ushort_t;
typedef unsigned int   uint_t;
typedef __attribute__((ext_vector_type(8))) short short8;   // 8 bf16 = 4 VGPR
typedef __attribute__((ext_vector_type(4))) float f32x4;

template<int N> struct IC { static constexpr int v = N; };

__device__ __forceinline__ float bf2f(ushort_t h){
  union { uint_t u; float f; } c; c.u = ((uint_t)h) << 16; return c.f;
}
__device__ __forceinline__ ushort_t f2bf(float f){
  union { float f; uint_t u; } c; c.f = f;
  uint_t u = c.u;
  u += 0x7fffu + ((u >> 16) & 1u);   // round-to-nearest-even
  return (ushort_t)(u >> 16);
}
__device__ __forceinline__ uint_t cvtpk(float a, float b){   // {bf16(b)<<16 | bf16(a)}
  uint_t r; asm("v_cvt_pk_bf16_f32 %0, %1, %2" : "=v"(r) : "v"(a), "v"(b)); return r;
}
// swizzled byte offset into 64B-row LDS tile (row-dep XOR of 16B slot)
__device__ __forceinline__ int swz(int row, int byteoff){
  return row*64 + ((((byteoff >> 4) ^ ((row >> 1) & 3)) & 3) << 4) + (byteoff & 15);
}
__device__ __forceinline__ void dma16(const ushort_t* src, ushort_t* dst){
  __builtin_amdgcn_global_load_lds(
      (const __attribute__((address_space(1))) uint_t*)src,
      (__attribute__((address_space(3))) uint_t*)dst, 16, 0, 0);   // imm offset MUST be 0
}

// ---------------- BatchNorm statistics ----------------
__global__ __launch_bounds__(256) void bn_partial(const float2* __restrict__ vel,
                                                  float* __restrict__ part){
  __shared__ float s[256][4];
  const int t = threadIdx.x;
  const int id = blockIdx.x * 256 + t;
  float2 v = vel[id];
  s[t][0] = v.x; s[t][1] = v.y; s[t][2] = v.x * v.x; s[t][3] = v.y * v.y;
  __syncthreads();
  for (int off = 128; off > 0; off >>= 1){
    if (t < off){
      s[t][0] += s[t+off][0]; s[t][1] += s[t+off][1];
      s[t][2] += s[t+off][2]; s[t][3] += s[t+off][3];
    }
    __syncthreads();
  }
  if (t == 0){
    part[blockIdx.x*4+0] = s[0][0]; part[blockIdx.x*4+1] = s[0][1];
    part[blockIdx.x*4+2] = s[0][2]; part[blockIdx.x*4+3] = s[0][3];
  }
}

__global__ __launch_bounds__(256) void bn_final(const float* __restrict__ part,
                                                const float* __restrict__ gamma,
                                                const float* __restrict__ beta,
                                                float* __restrict__ stats){
  __shared__ float s[256][4];
  const int t = threadIdx.x;
  const float4 p = reinterpret_cast<const float4*>(part)[t];
  s[t][0] = p.x; s[t][1] = p.y; s[t][2] = p.z; s[t][3] = p.w;
  __syncthreads();
  for (int off = 128; off > 0; off >>= 1){
    if (t < off){
      s[t][0] += s[t+off][0]; s[t][1] += s[t+off][1];
      s[t][2] += s[t+off][2]; s[t][3] += s[t+off][3];
    }
    __syncthreads();
  }
  if (t == 0){
    const float invN = 1.0f / 65536.0f;
    float m0 = s[0][0]*invN, m1 = s[0][1]*invN;
    float var0 = s[0][2]*invN - m0*m0;
    float var1 = s[0][3]*invN - m1*m1;
    float A0 = gamma[0] * rsqrtf(var0 + 1e-5f);
    float A1 = gamma[1] * rsqrtf(var1 + 1e-5f);
    stats[0] = A0; stats[1] = beta[0] - A0*m0;
    stats[2] = A1; stats[3] = beta[1] - A1*m1;
    stats[4] = beta[2];   // z-col of vel3 is identically 0
  }
}

__global__ __launch_bounds__(256) void feats_kernel(const float2* __restrict__ vel,
                                                    const float* __restrict__ stats,
                                                    float4* __restrict__ fin){
  const int id = blockIdx.x * 256 + threadIdx.x;
  float2 v = vel[id];
  float A0 = stats[0], B0 = stats[1], A1 = stats[2], B1 = stats[3], C2 = stats[4];
  fin[id] = make_float4(A0*v.x + B0, A1*v.y + B1, C2, 0.0f);
}

// ---------------- filter geometry: (win, gx, gy) per (n,k) ----------------
__global__ __launch_bounds__(256) void geo_kernel(const float2* __restrict__ pos,
                                                  float4* __restrict__ wgeo){
  const int id = blockIdx.x * 256 + threadIdx.x;   // < N*9 exactly
  const int n = id / 9;
  const int k = id - n * 9;
  const int i = n >> 8, j = n & 255;
  const int di = k / 3 - 1, dj = k - (k/3)*3 - 1;
  const int ni = i + di, nj = j + dj;
  const bool valid = (ni >= 0) && (ni < GRIDW) && (nj >= 0) && (nj < GRIDW);
  const int mi = min(max(ni, 0), GRIDW-1), mj = min(max(nj, 0), GRIDW-1);
  const int m = (mi << 8) | mj;
  float2 pn = pos[n], pm = pos[m];
  float x = (pm.x - pn.x) * (1.0f / RADI);
  float y = (pm.y - pn.y) * (1.0f / RADI);
  float sq = x*x + y*y;                 // z == 0 throughout
  bool nz = sq > EPSF;
  float cx = nz ? x : 0.0f;
  float cy = nz ? y : 0.0f;
  float rr = cx*cx + cy*cy;
  float r = sqrtf(fmaxf(rr, EPSF));
  float acx = fabsf(cx), acy = fabsf(cy);
  bool condx = acx >= acy;
  float dx  = (acx > 1e-9f) ? cx : 1.0f;
  float dyv = (acy > 1e-9f) ? cy : 1.0f;
  const float fop = 1.27323954473516268615f;   // 4/pi
  float sx = (cx > 0.f) ? 1.f : ((cx < 0.f) ? -1.f : 0.f);
  float sy = (cy > 0.f) ? 1.f : ((cy < 0.f) ? -1.f : 0.f);
  float u, v;
  if (condx){ u = sx * r;                    v = sx * r * fop * atanf(cy/dx); }
  else      { u = sy * r * fop * atanf(cx/dyv); v = sy * r; }
  if (rr <= EPSF){ u = 0.0f; v = 0.0f; }
  float gx = fminf(fmaxf((u + 1.0f) * 1.5f, 0.0f), 3.0f);
  float gy = fminf(fmaxf((v + 1.0f) * 1.5f, 0.0f), 3.0f);
  float pw = 1.0f - fminf(fmaxf(sq, 0.0f), 1.0f);
  float win = pw * pw * pw;
  win = (sq <= 1.0f && valid) ? win : 0.0f;
  wgeo[id] = make_float4(win, gx, gy, 0.0f);
}

// ---- weight pre-transpose via LDS tiles: Wt[d][kk], kk = c*16+g | 16Cin+c ----
template<int Cin, int Cout>
__global__ __launch_bounds__(256) void wprep(const float* __restrict__ cw,
                                             const float* __restrict__ dw,
                                             ushort_t* __restrict__ Wt){
  constexpr int K = 17*Cin;
  constexpr int NKT = K/32;
  const int bt = blockIdx.x;
  const int d0 = (bt / NKT) * 64;
  const int k0 = (bt % NKT) * 32;
  __shared__ ushort_t t[32][72];
  const int tid = threadIdx.x;
  const int dl = tid & 63;
  for (int r = tid >> 6; r < 32; r += 4){
    const int kk = k0 + r;
    float v;
    if (kk < 16*Cin){ int c = kk >> 4, g = kk & 15; v = cw[(size_t)(g*Cin + c)*Cout + d0 + dl]; }
    else v = dw[(size_t)(kk - 16*Cin)*Cout + d0 + dl];
    t[r][dl] = f2bf(v);
  }
  __syncthreads();
  const int d = tid >> 2, seg = tid & 3;
  uint4 o;
  ushort_t* op = (ushort_t*)&o;
  #pragma unroll
  for (int e = 0; e < 8; ++e) op[e] = t[seg*8 + e][d];
  *reinterpret_cast<uint4*>(Wt + (size_t)(d0 + d)*K + k0 + seg*8) = o;
}

// ---------------- layer 0: Cin=3 direct (VALU, small) ----------------
__global__ __launch_bounds__(256) void layer0_kernel(
    const float4* __restrict__ fin, const float4* __restrict__ wgeo,
    const float* __restrict__ cw, const float* __restrict__ cb,
    const float* __restrict__ dw, const float* __restrict__ db,
    ushort_t* __restrict__ f0){
  __shared__ float Wc[48*32];
  __shared__ float Wd[96];
  __shared__ float Bs[64];
  const int tid = threadIdx.x;
  for (int idx = tid; idx < 1536; idx += 256) Wc[idx] = cw[idx];
  if (tid < 96) Wd[tid] = dw[tid];
  if (tid < 32){ Bs[tid] = cb[tid]; Bs[32+tid] = db[tid]; }
  __syncthreads();
  const int p = tid >> 3, q = tid & 7;
  const int n = blockIdx.x * 32 + p;
  const int i = n >> 8, j = n & 255;
  float A[48];
  #pragma unroll
  for (int a = 0; a < 48; ++a) A[a] = 0.0f;
  const float4 fc = fin[n];
  #pragma unroll
  for (int k = 0; k < 9; ++k){
    const int di = k/3 - 1, dj = k - (k/3)*3 - 1;
    const int mi = min(max(i+di,0),255), mj = min(max(j+dj,0),255);
    const int m = (mi << 8) | mj;
    float4 geo = wgeo[n*9 + k];
    float4 fm = fin[m];
    float wx[4], wy[4];
    #pragma unroll
    for (int a = 0; a < 4; ++a){
      wx[a] = fmaxf(1.0f - fabsf(geo.y - (float)a), 0.0f);
      wy[a] = fmaxf(1.0f - fabsf(geo.z - (float)a), 0.0f);
    }
    #pragma unroll
    for (int ix = 0; ix < 4; ++ix)
      #pragma unroll
      for (int iy = 0; iy < 4; ++iy){
        float w = geo.x * wx[ix] * wy[iy];
        int g = ix*4 + iy;
        A[g*3+0] += w * fm.x; A[g*3+1] += w * fm.y; A[g*3+2] += w * fm.z;
      }
  }
  if (q < 4){
    #pragma unroll
    for (int jj = 0; jj < 8; ++jj){
      int d = q*8 + jj;
      float acc = Bs[d];
      #pragma unroll
      for (int a = 0; a < 48; ++a) acc += A[a] * Wc[a*32 + d];
      f0[n*64 + d] = f2bf(acc);
    }
  } else {
    #pragma unroll
    for (int jj = 0; jj < 8; ++jj){
      int d2 = (q-4)*8 + jj;
      float acc = Bs[32+d2] + fc.x*Wd[0*32+d2] + fc.y*Wd[1*32+d2] + fc.z*Wd[2*32+d2];
      f0[n*64 + 32 + d2] = f2bf(acc);
    }
  }
}

// ------ MFMA conv+dense layers: 512 threads, 8 waves (2M x 4N), shared A ------
template<int Cin, int Cout, bool RESID>
__global__ __launch_bounds__(512) void conv_mfma(
    const ushort_t* __restrict__ fin, const float4* __restrict__ wgeo,
    const ushort_t* __restrict__ Wt,
    const float* __restrict__ cb, const float* __restrict__ db,
    ushort_t* __restrict__ fout){
  constexpr int K   = 17*Cin;
  constexpr int NCC = Cin/2;            // conv chunks
  constexpr int NCH = K/32;             // total chunks (even for all layers)
  constexpr int HSTR = 137;             // halo row stride in dwords
  constexpr int MF  = 2;                // 2 x 16 rows per wave (Mbase = cl*32)
  constexpr int NF  = Cout/64;          // N frags per wave (Nbase = gq*NF*16)
  constexpr int NDMA = Cout/16;         // 16-row dma groups per chunk
  constexpr int WITER = (NDMA + 7)/8;

  __shared__ uint_t halo32[16*HSTR];                  // 8768 B
  __shared__ __align__(16) ushort_t A_lds[2][64*32];  // 2 x 4 KB, swizzled
  __shared__ __align__(16) char W_lds[2][Cout*64];    // 2 x Cout*64 B, swizzled

  const int tid = threadIdx.x;
  const int i0 = (blockIdx.x >> 3) * 2;
  const int j0 = (blockIdx.x & 7) * 32;

  auto stage = [&](int ph){
    for (int idx = tid; idx < 544; idx += 512){
      const int loc = idx >> 2, c8l = idx & 3;
      const int r = loc / 34, col = loc - r*34;
      const int gi = min(max(i0 - 1 + r, 0), 255);
      const int gj = min(max(j0 - 1 + col, 0), 255);
      const int mm = (gi << 8) | gj;
      uint4 v = *reinterpret_cast<const uint4*>(fin + (size_t)mm*Cin + ph*32 + c8l*8);
      const uint_t* vp = (const uint_t*)&v;
      #pragma unroll
      for (int q = 0; q < 4; ++q){
        uint_t u = vp[q];
        uint_t lo = (u & 0x00008000u) ? 0u : (u & 0x0000FFFFu);
        uint_t hi = (u & 0x80000000u) ? 0u : (u & 0xFFFF0000u);
        halo32[(c8l*4 + q)*HSTR + loc] = hi | lo;
      }
    }
  };

  const int m  = tid & 63;              // local point == lane
  const int wv = tid >> 6;              // wave id 0..7
  const int gq = wv & 3;                // g-quarter AND wn
  const int cl = wv >> 2;               // channel-in-pair AND wm
  const int lane = m;
  const int lr = lane & 15, lg = lane >> 4;
  const int n_m = ((i0 + (m >> 5)) << 8) + j0 + (m & 31);
  const int ctr = (1 + (m >> 5))*34 + 1 + (m & 31);

  stage(0);
  f32x4 tap[9];
  #pragma unroll
  for (int k = 0; k < 9; ++k){
    float4 geo = wgeo[(size_t)n_m*9 + k];
    float wxg = fmaxf(1.0f - fabsf(geo.y - (float)gq), 0.0f);
    float s = geo.x * wxg;
    tap[k].x = s * fmaxf(1.0f - fabsf(geo.z - 0.0f), 0.0f);
    tap[k].y = s * fmaxf(1.0f - fabsf(geo.z - 1.0f), 0.0f);
    tap[k].z = s * fmaxf(1.0f - fabsf(geo.z - 2.0f), 0.0f);
    tap[k].w = s * fmaxf(1.0f - fabsf(geo.z - 3.0f), 0.0f);
  }

  const int Mbase = cl * 32;
  const int Nbase = gq * (NF*16);

  int aoff[MF], woff[NF];
  #pragma unroll
  for (int mi = 0; mi < MF; ++mi) aoff[mi] = swz(Mbase + mi*16 + lr, lg*16);
  #pragma unroll
  for (int ni = 0; ni < NF; ++ni) woff[ni] = swz(Nbase + ni*16 + lr, lg*16);
  const int sc  = swz(m, cl*32 + gq*8);   // conv-chunk uint2 slot
  const int sdn = swz(m, wv*8);           // dense-chunk uint2 slot

  // W DMA source pointers (chunk advance folded into pointer; imm offset = 0)
  const ushort_t* wsrc[WITER];
  #pragma unroll
  for (int t = 0; t < WITER; ++t){
    const int c = wv + t*8;
    const int cc = (c < NDMA) ? c : 0;
    const int dl = cc*16 + (lane >> 2);
    const int qs = (lane & 3) ^ ((dl >> 1) & 3);
    wsrc[t] = Wt + (size_t)dl*K + qs*8;
  }

  f32x4 acc[MF][NF];
  #pragma unroll
  for (int a = 0; a < MF; ++a)
    #pragma unroll
    for (int b = 0; b < NF; ++b) acc[a][b] = (f32x4){0.f,0.f,0.f,0.f};
  float bias[NF];
  #pragma unroll
  for (int ni = 0; ni < NF; ++ni){
    const int d = Nbase + ni*16 + lr;
    bias[ni] = cb[d] + db[d];
  }

  auto buildA = [&](auto BC, int ch){
    constexpr int B = decltype(BC)::v;
    char* Ab = (char*)A_lds[B];
    if (ch < NCC){
      const uint_t* hb = &halo32[(ch & 15)*HSTR + ctr - 35];
      float a0 = 0.f, a1 = 0.f, a2 = 0.f, a3 = 0.f;
      #pragma unroll
      for (int kr = 0; kr < 3; ++kr)
        #pragma unroll
        for (int kc = 0; kc < 3; ++kc){
          const uint_t u = hb[kr*34 + kc];
          const float fv = __uint_as_float(cl ? (u & 0xFFFF0000u) : (u << 16));
          const f32x4 tp = tap[kr*3 + kc];
          a0 += tp.x*fv; a1 += tp.y*fv; a2 += tp.z*fv; a3 += tp.w*fv;
        }
      uint2 p;
      p.x = cvtpk(a0, a1); p.y = cvtpk(a2, a3);
      *reinterpret_cast<uint2*>(Ab + sc) = p;
    } else {
      const int cd0 = (ch - NCC)*32 + wv*4;   // 4 dense channels per thread
      uint2 u = *reinterpret_cast<const uint2*>(fin + (size_t)n_m*Cin + cd0);
      uint_t* up = (uint_t*)&u;
      #pragma unroll
      for (int q = 0; q < 2; ++q){
        uint_t w = up[q];
        uint_t lo = (w & 0x00008000u) ? 0u : (w & 0x0000FFFFu);
        uint_t hi = (w & 0x80000000u) ? 0u : (w & 0xFFFF0000u);
        up[q] = hi | lo;
      }
      *reinterpret_cast<uint2*>(Ab + sdn) = u;
    }
  };

  auto issueW = [&](auto OC, int b){
    constexpr int OFS = decltype(OC)::v;      // byte advance of chunk
    #pragma unroll
    for (int t = 0; t < WITER; ++t){
      const int c = wv + t*8;
      if (c < NDMA)
        dma16(wsrc[t] + OFS/2, (ushort_t*)&W_lds[b][c*1024]);
    }
  };

  auto body = [&](auto BC, auto OC, int ch, bool prep){
    constexpr int B = decltype(BC)::v;
    __syncthreads();                     // A(ch)/W(ch) ready (vmcnt drained)
    short8 af[MF], bfr[NF];
    const char* Ab = (const char*)A_lds[B];
    const char* Wb = (const char*)W_lds[B];
    #pragma unroll
    for (int mi = 0; mi < MF; ++mi)
      af[mi] = *reinterpret_cast<const short8*>(Ab + aoff[mi]);
    #pragma unroll
    for (int ni = 0; ni < NF; ++ni)
      bfr[ni] = *reinterpret_cast<const short8*>(Wb + woff[ni]);
    if (prep) issueW(OC, B^1);
    #pragma unroll
    for (int mi = 0; mi < MF; ++mi)
      #pragma unroll
      for (int ni = 0; ni < NF; ++ni)
        acc[mi][ni] = __builtin_amdgcn_mfma_f32_16x16x32_bf16(
            af[mi], bfr[ni], acc[mi][ni], 0, 0, 0);
    if (prep) buildA(IC<B^1>{}, ch + 1);
  };

  __syncthreads();                       // halo(0) visible
  issueW(IC<0>{}, 0);
  buildA(IC<0>{}, 0);

  for (int ch2 = 0; ch2 < NCH; ch2 += 2){
    body(IC<0>{}, IC<64>{}, ch2, true);
    const int nxt = ch2 + 2;
    if ((nxt < NCC) && ((nxt & 15) == 0)){ __syncthreads(); stage(nxt >> 4); }
    body(IC<1>{}, IC<128>{}, ch2 + 1, nxt < NCH);
    #pragma unroll
    for (int t = 0; t < WITER; ++t) wsrc[t] += 64;   // advance 128 bytes
  }

  // epilogue: + biases (+ residual), store bf16
  #pragma unroll
  for (int mi = 0; mi < MF; ++mi){
    #pragma unroll
    for (int r = 0; r < 4; ++r){
      const int row = Mbase + mi*16 + lg*4 + r;
      const int n = ((i0 + (row >> 5)) << 8) + j0 + (row & 31);
      #pragma unroll
      for (int ni = 0; ni < NF; ++ni){
        const int d = Nbase + ni*16 + lr;
        float v = acc[mi][ni][r] + bias[ni];
        if (RESID) v += bf2f(fin[(size_t)n*Cin + d]);
        fout[(size_t)n*Cout + d] = f2bf(v);
      }
    }
  }
}

// ---------------- layer 4 (Cout=1): y[g][m] = relu(f3[m]) . Wy[g] ----------------
__global__ __launch_bounds__(256) void layer4a_kernel(
    const ushort_t* __restrict__ f3, const float* __restrict__ cw4,
    const float* __restrict__ dw4, float* __restrict__ y){
  __shared__ float Wy[17*256];
  __shared__ float red[4*1088];
  const int tid = threadIdx.x;
  for (int idx = tid; idx < 4096; idx += 256) Wy[idx] = cw4[idx];
  Wy[4096 + tid] = dw4[tid];
  __syncthreads();
  const int m = tid & 63, q = tid >> 6;
  const int n = blockIdx.x * 64 + m;
  const float4* Wy4 = reinterpret_cast<const float4*>(Wy);
  float acc[17];
  #pragma unroll
  for (int g = 0; g < 17; ++g) acc[g] = 0.0f;
  const uint4* frow = reinterpret_cast<const uint4*>(f3 + (size_t)n*256 + q*64);
  #pragma unroll
  for (int it = 0; it < 8; ++it){
    uint4 hv = frow[it];
    const uint_t* up = (const uint_t*)&hv;
    float f[8];
    #pragma unroll
    for (int w = 0; w < 4; ++w){
      uint_t u = up[w];
      f[2*w+0] = (u & 0x00008000u) ? 0.0f : __uint_as_float(u << 16);
      f[2*w+1] = (u & 0x80000000u) ? 0.0f : __uint_as_float(u & 0xFFFF0000u);
    }
    const int i4 = q*16 + it*2;
    #pragma unroll
    for (int g = 0; g < 17; ++g){
      float4 w0 = Wy4[g*64 + i4];
      float4 w1 = Wy4[g*64 + i4 + 1];
      acc[g] += w0.x*f[0] + w0.y*f[1] + w0.z*f[2] + w0.w*f[3]
              + w1.x*f[4] + w1.y*f[5] + w1.z*f[6] + w1.w*f[7];
    }
  }
  #pragma unroll
  for (int g = 0; g < 17; ++g) red[q*1088 + m*17 + g] = acc[g];
  __syncthreads();
  for (int idx = tid; idx < 1088; idx += 256){
    const int g = idx >> 6, mm = idx & 63;
    float s = red[0*1088 + mm*17 + g] + red[1*1088 + mm*17 + g]
            + red[2*1088 + mm*17 + g] + red[3*1088 + mm*17 + g];
    y[g*65536 + blockIdx.x*64 + mm] = s;
  }
}

__global__ __launch_bounds__(256) void layer4b_kernel(
    const float4* __restrict__ wgeo, const float* __restrict__ y,
    const float* __restrict__ cb4, const float* __restrict__ db4,
    float* __restrict__ out){
  const int n = blockIdx.x * 256 + threadIdx.x;
  const int i = n >> 8, j = n & 255;
  float acc = cb4[0] + db4[0] + y[16*65536 + n];
  #pragma unroll
  for (int k = 0; k < 9; ++k){
    const int di = k/3 - 1, dj = k - (k/3)*3 - 1;
    const int mi = min(max(i+di,0),255), mj = min(max(j+dj,0),255);
    const int m = (mi << 8) | mj;
    float4 geo = wgeo[n*9 + k];
    float wx[4], wy[4];
    #pragma unroll
    for (int a = 0; a < 4; ++a){
      wx[a] = fmaxf(1.0f - fabsf(geo.y - (float)a), 0.0f);
      wy[a] = fmaxf(1.0f - fabsf(geo.z - (float)a), 0.0f);
    }
    float s = 0.0f;
    #pragma unroll
    for (int ix = 0; ix < 4; ++ix){
      float sy = 0.0f;
      #pragma unroll
      for (int iy = 0; iy < 4; ++iy) sy += wy[iy] * y[(ix*4 + iy)*65536 + m];
      s += wx[ix] * sy;
    }
    acc += geo.x * s;
  }
  out[n] = tanhf(acc) * 0.8f + 1.0f;   // output f32
}

// ---------------- host launcher ----------------
extern "C" void kernel_launch(void* const* d_in, const int* in_sizes, int n_in,
                              void* d_out, int out_size, void* d_ws, size_t ws_size,
                              hipStream_t stream){
  const float* pos = (const float*)d_in[0];
  const float* vel = (const float*)d_in[1];
  const float* bng = (const float*)d_in[4];
  const float* bnb = (const float*)d_in[5];
  const bool dict = (in_sizes[8] == 96);
  const float *cwp[5], *cbp[5], *dwp[5], *dbp[5];
  for (int l = 0; l < 5; ++l){
    if (dict){
      cwp[l] = (const float*)d_in[6 + 4*l]; cbp[l] = (const float*)d_in[7 + 4*l];
      dwp[l] = (const float*)d_in[8 + 4*l]; dbp[l] = (const float*)d_in[9 + 4*l];
    } else {
      cwp[l] = (const float*)d_in[6 + 2*l];  cbp[l] = (const float*)d_in[7 + 2*l];
      dwp[l] = (const float*)d_in[16 + 2*l]; dbp[l] = (const float*)d_in[17 + 2*l];
    }
  }
  char* wsb = (char*)d_ws;
  float*    part  = (float*)   (wsb + 0);
  float*    stats = (float*)   (wsb + 4096);
  float4*   fin   = (float4*)  (wsb + 8192);
  float4*   wgeo  = (float4*)  (wsb + 1056768);
  ushort_t* Wt1   = (ushort_t*)(wsb + 10493952);
  ushort_t* Wt2   = (ushort_t*)(wsb + 10633216);
  ushort_t* Wt3   = (ushort_t*)(wsb + 10911744);
  ushort_t* f0    = (ushort_t*)(wsb + 12025856);
  ushort_t* f1    = (ushort_t*)(wsb + 20414464);
  ushort_t* f2    = (ushort_t*)(wsb + 28803072);
  ushort_t* f3    = (ushort_t*)(wsb + 45580288);
  float*    y     = (float*)   (wsb + 12025856);   // overlays f0 (dead by layer4)
  float*    outp  = (float*)d_out;

  hipLaunchKernelGGL(bn_partial, dim3(256), dim3(256), 0, stream, (const float2*)vel, part);
  hipLaunchKernelGGL(bn_final, dim3(1), dim3(256), 0, stream, part, bng, bnb, stats);
  hipLaunchKernelGGL(feats_kernel, dim3(256), dim3(256), 0, stream, (const float2*)vel, stats, fin);
  hipLaunchKernelGGL(geo_kernel, dim3(2304), dim3(256), 0, stream, (const float2*)pos, wgeo);
  hipLaunchKernelGGL((wprep<64,64>),   dim3(34),  dim3(256), 0, stream, cwp[1], dwp[1], Wt1);
  hipLaunchKernelGGL((wprep<64,128>),  dim3(68),  dim3(256), 0, stream, cwp[2], dwp[2], Wt2);
  hipLaunchKernelGGL((wprep<128,256>), dim3(272), dim3(256), 0, stream, cwp[3], dwp[3], Wt3);
  hipLaunchKernelGGL(layer0_kernel, dim3(2048), dim3(256), 0, stream,
                     fin, wgeo, cwp[0], cbp[0], dwp[0], dbp[0], f0);
  hipLaunchKernelGGL((conv_mfma<64,64,true>),   dim3(1024), dim3(512), 0, stream,
                     f0, wgeo, Wt1, cbp[1], dbp[1], f1);
  hipLaunchKernelGGL((conv_mfma<64,128,false>), dim3(1024), dim3(512), 0, stream,
                     f1, wgeo, Wt2, cbp[2], dbp[2], f2);
  hipLaunchKernelGGL((conv_mfma<128,256,false>),dim3(1024), dim3(512), 0, stream,
                     f2, wgeo, Wt3, cbp[3], dbp[3], f3);
  hipLaunchKernelGGL(layer4a_kernel, dim3(1024), dim3(256), 0, stream, f3, cwp[4], dwp[4], y);
  hipLaunchKernelGGL(layer4b_kernel, dim3(256), dim3(256), 0, stream, wgeo, y, cbp[4], dbp[4], outp);
}

// Round 11
// 249.023 us; speedup vs baseline: 1.4676x; 1.4676x over previous
//
#include <hip/hip_runtime.h>
#include <hip/hip_bf16.h>
#include <cstdint>

// ParaNet_Point round-11: W via global->VGPR fragment stream (no W_lds/DMA).
// Wfrag pre-packed in MFMA B-fragment order: (chunk, 16-col grp) = 1KB blocks;
// per-wave loads are 1KB fully-coalesced, L2-resident. LDS = halo + A dbuf
// (17KB). Waves: WGM=1 x WGN=4 (MF=4, NF=Cout/64) -> unique cols per wave,
// bfr<=16 VGPR, acc 64 AGPR, target 3 waves/SIMD. A built once (r9 lesson),
// 4-wave blocks (r10 lesson). Numerics identical to r9 -> absmax 0.0078125.

#define GRIDW 256
#define NPTS  65536
#define RADI  0.0125f
#define EPSF  1e-12f

typedef unsigned short ushort_t;
typedef unsigned int   uint_t;
typedef __attribute__((ext_vector_type(8))) short short8;   // 8 bf16 = 4 VGPR
typedef __attribute__((ext_vector_type(4))) float f32x4;

template<int N> struct IC { static constexpr int v = N; };

__device__ __forceinline__ float bf2f(ushort_t h){
  union { uint_t u; float f; } c; c.u = ((uint_t)h) << 16; return c.f;
}
__device__ __forceinline__ ushort_t f2bf(float f){
  union { float f; uint_t u; } c; c.f = f;
  uint_t u = c.u;
  u += 0x7fffu + ((u >> 16) & 1u);   // round-to-nearest-even
  return (ushort_t)(u >> 16);
}
__device__ __forceinline__ uint_t cvtpk(float a, float b){   // {bf16(b)<<16 | bf16(a)}
  uint_t r; asm("v_cvt_pk_bf16_f32 %0, %1, %2" : "=v"(r) : "v"(a), "v"(b)); return r;
}
// swizzled byte offset into 64B-row LDS tile (row-dep XOR of 16B slot)
__device__ __forceinline__ int swz(int row, int byteoff){
  return row*64 + ((((byteoff >> 4) ^ ((row >> 1) & 3)) & 3) << 4) + (byteoff & 15);
}

// ---------------- BatchNorm statistics ----------------
__global__ __launch_bounds__(256) void bn_partial(const float2* __restrict__ vel,
                                                  float* __restrict__ part){
  __shared__ float s[256][4];
  const int t = threadIdx.x;
  const int id = blockIdx.x * 256 + t;
  float2 v = vel[id];
  s[t][0] = v.x; s[t][1] = v.y; s[t][2] = v.x * v.x; s[t][3] = v.y * v.y;
  __syncthreads();
  for (int off = 128; off > 0; off >>= 1){
    if (t < off){
      s[t][0] += s[t+off][0]; s[t][1] += s[t+off][1];
      s[t][2] += s[t+off][2]; s[t][3] += s[t+off][3];
    }
    __syncthreads();
  }
  if (t == 0){
    part[blockIdx.x*4+0] = s[0][0]; part[blockIdx.x*4+1] = s[0][1];
    part[blockIdx.x*4+2] = s[0][2]; part[blockIdx.x*4+3] = s[0][3];
  }
}

__global__ __launch_bounds__(256) void bn_final(const float* __restrict__ part,
                                                const float* __restrict__ gamma,
                                                const float* __restrict__ beta,
                                                float* __restrict__ stats){
  __shared__ float s[256][4];
  const int t = threadIdx.x;
  const float4 p = reinterpret_cast<const float4*>(part)[t];
  s[t][0] = p.x; s[t][1] = p.y; s[t][2] = p.z; s[t][3] = p.w;
  __syncthreads();
  for (int off = 128; off > 0; off >>= 1){
    if (t < off){
      s[t][0] += s[t+off][0]; s[t][1] += s[t+off][1];
      s[t][2] += s[t+off][2]; s[t][3] += s[t+off][3];
    }
    __syncthreads();
  }
  if (t == 0){
    const float invN = 1.0f / 65536.0f;
    float m0 = s[0][0]*invN, m1 = s[0][1]*invN;
    float var0 = s[0][2]*invN - m0*m0;
    float var1 = s[0][3]*invN - m1*m1;
    float A0 = gamma[0] * rsqrtf(var0 + 1e-5f);
    float A1 = gamma[1] * rsqrtf(var1 + 1e-5f);
    stats[0] = A0; stats[1] = beta[0] - A0*m0;
    stats[2] = A1; stats[3] = beta[1] - A1*m1;
    stats[4] = beta[2];   // z-col of vel3 is identically 0
  }
}

__global__ __launch_bounds__(256) void feats_kernel(const float2* __restrict__ vel,
                                                    const float* __restrict__ stats,
                                                    float4* __restrict__ fin){
  const int id = blockIdx.x * 256 + threadIdx.x;
  float2 v = vel[id];
  float A0 = stats[0], B0 = stats[1], A1 = stats[2], B1 = stats[3], C2 = stats[4];
  fin[id] = make_float4(A0*v.x + B0, A1*v.y + B1, C2, 0.0f);
}

// ---------------- filter geometry: (win, gx, gy) per (n,k) ----------------
__global__ __launch_bounds__(256) void geo_kernel(const float2* __restrict__ pos,
                                                  float4* __restrict__ wgeo){
  const int id = blockIdx.x * 256 + threadIdx.x;   // < N*9 exactly
  const int n = id / 9;
  const int k = id - n * 9;
  const int i = n >> 8, j = n & 255;
  const int di = k / 3 - 1, dj = k - (k/3)*3 - 1;
  const int ni = i + di, nj = j + dj;
  const bool valid = (ni >= 0) && (ni < GRIDW) && (nj >= 0) && (nj < GRIDW);
  const int mi = min(max(ni, 0), GRIDW-1), mj = min(max(nj, 0), GRIDW-1);
  const int m = (mi << 8) | mj;
  float2 pn = pos[n], pm = pos[m];
  float x = (pm.x - pn.x) * (1.0f / RADI);
  float y = (pm.y - pn.y) * (1.0f / RADI);
  float sq = x*x + y*y;                 // z == 0 throughout
  bool nz = sq > EPSF;
  float cx = nz ? x : 0.0f;
  float cy = nz ? y : 0.0f;
  float rr = cx*cx + cy*cy;
  float r = sqrtf(fmaxf(rr, EPSF));
  float acx = fabsf(cx), acy = fabsf(cy);
  bool condx = acx >= acy;
  float dx  = (acx > 1e-9f) ? cx : 1.0f;
  float dyv = (acy > 1e-9f) ? cy : 1.0f;
  const float fop = 1.27323954473516268615f;   // 4/pi
  float sx = (cx > 0.f) ? 1.f : ((cx < 0.f) ? -1.f : 0.f);
  float sy = (cy > 0.f) ? 1.f : ((cy < 0.f) ? -1.f : 0.f);
  float u, v;
  if (condx){ u = sx * r;                    v = sx * r * fop * atanf(cy/dx); }
  else      { u = sy * r * fop * atanf(cx/dyv); v = sy * r; }
  if (rr <= EPSF){ u = 0.0f; v = 0.0f; }
  float gx = fminf(fmaxf((u + 1.0f) * 1.5f, 0.0f), 3.0f);
  float gy = fminf(fmaxf((v + 1.0f) * 1.5f, 0.0f), 3.0f);
  float pw = 1.0f - fminf(fmaxf(sq, 0.0f), 1.0f);
  float win = pw * pw * pw;
  win = (sq <= 1.0f && valid) ? win : 0.0f;
  wgeo[id] = make_float4(win, gx, gy, 0.0f);
}

// -- W pre-pack into MFMA B-fragment order --------------------------------
// Wfrag[((ch*G + grp)*64 + l)*8 + e] = bf16(W[kk = ch*32 + (l>>4)*8 + e]
//                                          [d  = grp*16 + (l&15)])
// kk<16Cin: conv (c=kk>>4, g=kk&15); else dense row kk-16Cin.
template<int Cin, int Cout>
__global__ __launch_bounds__(256) void wprep(const float* __restrict__ cw,
                                             const float* __restrict__ dw,
                                             ushort_t* __restrict__ Wf){
  constexpr int G = Cout/16;
  const int id = blockIdx.x*256 + threadIdx.x;     // grid sized exactly
  const int ch = id / (G*64);
  const int r  = id - ch*G*64;
  const int grp = r >> 6, l = r & 63;
  const int d  = grp*16 + (l & 15);
  const int kb = ch*32 + (l >> 4)*8;
  ushort_t o[8];
  #pragma unroll
  for (int e = 0; e < 8; ++e){
    const int kk = kb + e;
    float v;
    if (kk < 16*Cin){ int c = kk >> 4, g = kk & 15; v = cw[(size_t)(g*Cin + c)*Cout + d]; }
    else v = dw[(size_t)(kk - 16*Cin)*Cout + d];
    o[e] = f2bf(v);
  }
  *reinterpret_cast<uint4*>(Wf + (size_t)id*8) = *reinterpret_cast<uint4*>(o);
}

// ---------------- layer 0: Cin=3 direct (VALU, small) ----------------
__global__ __launch_bounds__(256) void layer0_kernel(
    const float4* __restrict__ fin, const float4* __restrict__ wgeo,
    const float* __restrict__ cw, const float* __restrict__ cb,
    const float* __restrict__ dw, const float* __restrict__ db,
    ushort_t* __restrict__ f0){
  __shared__ float Wc[48*32];
  __shared__ float Wd[96];
  __shared__ float Bs[64];
  const int tid = threadIdx.x;
  for (int idx = tid; idx < 1536; idx += 256) Wc[idx] = cw[idx];
  if (tid < 96) Wd[tid] = dw[tid];
  if (tid < 32){ Bs[tid] = cb[tid]; Bs[32+tid] = db[tid]; }
  __syncthreads();
  const int p = tid >> 3, q = tid & 7;
  const int n = blockIdx.x * 32 + p;
  const int i = n >> 8, j = n & 255;
  float A[48];
  #pragma unroll
  for (int a = 0; a < 48; ++a) A[a] = 0.0f;
  const float4 fc = fin[n];
  #pragma unroll
  for (int k = 0; k < 9; ++k){
    const int di = k/3 - 1, dj = k - (k/3)*3 - 1;
    const int mi = min(max(i+di,0),255), mj = min(max(j+dj,0),255);
    const int m = (mi << 8) | mj;
    float4 geo = wgeo[n*9 + k];
    float4 fm = fin[m];
    float wx[4], wy[4];
    #pragma unroll
    for (int a = 0; a < 4; ++a){
      wx[a] = fmaxf(1.0f - fabsf(geo.y - (float)a), 0.0f);
      wy[a] = fmaxf(1.0f - fabsf(geo.z - (float)a), 0.0f);
    }
    #pragma unroll
    for (int ix = 0; ix < 4; ++ix)
      #pragma unroll
      for (int iy = 0; iy < 4; ++iy){
        float w = geo.x * wx[ix] * wy[iy];
        int g = ix*4 + iy;
        A[g*3+0] += w * fm.x; A[g*3+1] += w * fm.y; A[g*3+2] += w * fm.z;
      }
  }
  if (q < 4){
    #pragma unroll
    for (int jj = 0; jj < 8; ++jj){
      int d = q*8 + jj;
      float acc = Bs[d];
      #pragma unroll
      for (int a = 0; a < 48; ++a) acc += A[a] * Wc[a*32 + d];
      f0[n*64 + d] = f2bf(acc);
    }
  } else {
    #pragma unroll
    for (int jj = 0; jj < 8; ++jj){
      int d2 = (q-4)*8 + jj;
      float acc = Bs[32+d2] + fc.x*Wd[0*32+d2] + fc.y*Wd[1*32+d2] + fc.z*Wd[2*32+d2];
      f0[n*64 + 32 + d2] = f2bf(acc);
    }
  }
}

// ---- MFMA conv+dense layers: A in LDS (dbuf), W global->VGPR fragments ----
template<int Cin, int Cout, bool RESID>
__global__ __launch_bounds__(256) void conv_mfma(
    const ushort_t* __restrict__ fin, const float4* __restrict__ wgeo,
    const ushort_t* __restrict__ Wf,
    const float* __restrict__ cb, const float* __restrict__ db,
    ushort_t* __restrict__ fout){
  constexpr int K   = 17*Cin;
  constexpr int NCC = Cin/2;            // conv chunks
  constexpr int NCH = K/32;             // total chunks (even)
  constexpr int HSTR = 137;             // halo row stride in dwords
  constexpr int G   = Cout/16;          // 16-col groups per chunk
  constexpr int MF  = 4;                // every wave covers all 64 rows
  constexpr int NF  = Cout/64;          // col groups per wave

  __shared__ uint_t halo32[16*HSTR];                  // 8768 B
  __shared__ __align__(16) ushort_t A_lds[2][64*32];  // 2 x 4 KB, swizzled

  const int tid = threadIdx.x;
  const int i0 = (blockIdx.x >> 3) * 2;
  const int j0 = (blockIdx.x & 7) * 32;

  auto stage = [&](int ph){
    for (int idx = tid; idx < 544; idx += 256){
      const int loc = idx >> 2, c8l = idx & 3;
      const int r = loc / 34, col = loc - r*34;
      const int gi = min(max(i0 - 1 + r, 0), 255);
      const int gj = min(max(j0 - 1 + col, 0), 255);
      const int mm = (gi << 8) | gj;
      uint4 v = *reinterpret_cast<const uint4*>(fin + (size_t)mm*Cin + ph*32 + c8l*8);
      const uint_t* vp = (const uint_t*)&v;
      #pragma unroll
      for (int q = 0; q < 4; ++q){
        uint_t u = vp[q];
        uint_t lo = (u & 0x00008000u) ? 0u : (u & 0x0000FFFFu);
        uint_t hi = (u & 0x80000000u) ? 0u : (u & 0xFFFF0000u);
        halo32[(c8l*4 + q)*HSTR + loc] = hi | lo;
      }
    }
  };

  const int m  = tid & 63;              // local point == lane
  const int gq = tid >> 6;              // g-quarter AND wave id
  const int g0 = gq * 4;
  const int n_m = ((i0 + (m >> 5)) << 8) + j0 + (m & 31);
  const int lane = m;
  const int lr = lane & 15, lg = lane >> 4;
  const int ctr = (1 + (m >> 5))*34 + 1 + (m & 31);

  stage(0);
  f32x4 tap[9];
  #pragma unroll
  for (int k = 0; k < 9; ++k){
    float4 geo = wgeo[(size_t)n_m*9 + k];
    float wxg = fmaxf(1.0f - fabsf(geo.y - (float)gq), 0.0f);
    float s = geo.x * wxg;
    tap[k].x = s * fmaxf(1.0f - fabsf(geo.z - 0.0f), 0.0f);
    tap[k].y = s * fmaxf(1.0f - fabsf(geo.z - 1.0f), 0.0f);
    tap[k].z = s * fmaxf(1.0f - fabsf(geo.z - 2.0f), 0.0f);
    tap[k].w = s * fmaxf(1.0f - fabsf(geo.z - 3.0f), 0.0f);
  }

  const int Nbase = gq * (NF*16);       // wave's unique column block

  int aoff[MF];
  #pragma unroll
  for (int mi = 0; mi < MF; ++mi) aoff[mi] = swz(mi*16 + lr, lg*16);
  const int s0 = swz(m, 2*g0);
  const int s1 = swz(m, 32 + 2*g0);
  const int sd = swz(m, gq*16);

  // wave's W-fragment base: (chunk 0, grp = gq*NF + ni), lane slot
  const ushort_t* wp = Wf + (size_t)(gq*NF)*512 + lane*8;

  f32x4 acc[MF][NF];
  #pragma unroll
  for (int a = 0; a < MF; ++a)
    #pragma unroll
    for (int b = 0; b < NF; ++b) acc[a][b] = (f32x4){0.f,0.f,0.f,0.f};

  auto buildA = [&](auto BC, int ch){
    constexpr int B = decltype(BC)::v;
    char* Ab = (char*)A_lds[B];
    if (ch < NCC){
      const uint_t* hb = &halo32[(ch & 15)*HSTR + ctr - 35];
      float alo[4] = {0.f,0.f,0.f,0.f}, ahi[4] = {0.f,0.f,0.f,0.f};
      #pragma unroll
      for (int kr = 0; kr < 3; ++kr)
        #pragma unroll
        for (int kc = 0; kc < 3; ++kc){
          const uint_t u = hb[kr*34 + kc];
          const float flo = __uint_as_float(u << 16);
          const float fhi = __uint_as_float(u & 0xFFFF0000u);
          const f32x4 tp = tap[kr*3 + kc];
          alo[0] += tp.x*flo; ahi[0] += tp.x*fhi;
          alo[1] += tp.y*flo; ahi[1] += tp.y*fhi;
          alo[2] += tp.z*flo; ahi[2] += tp.z*fhi;
          alo[3] += tp.w*flo; ahi[3] += tp.w*fhi;
        }
      uint2 plo, phi;
      plo.x = cvtpk(alo[0], alo[1]); plo.y = cvtpk(alo[2], alo[3]);
      phi.x = cvtpk(ahi[0], ahi[1]); phi.y = cvtpk(ahi[2], ahi[3]);
      *reinterpret_cast<uint2*>(Ab + s0) = plo;
      *reinterpret_cast<uint2*>(Ab + s1) = phi;
    } else {
      const int cd0 = (ch - NCC)*32 + gq*8;   // 8 dense channels per thread
      uint4 u = *reinterpret_cast<const uint4*>(fin + (size_t)n_m*Cin + cd0);
      uint_t* up = (uint_t*)&u;
      #pragma unroll
      for (int q = 0; q < 4; ++q){
        uint_t w = up[q];
        uint_t lo = (w & 0x00008000u) ? 0u : (w & 0x0000FFFFu);
        uint_t hi = (w & 0x80000000u) ? 0u : (w & 0xFFFF0000u);
        up[q] = hi | lo;
      }
      *reinterpret_cast<uint4*>(Ab + sd) = u;
    }
  };

  auto body = [&](auto BC, int ch, bool prep){
    constexpr int B = decltype(BC)::v;
    __syncthreads();                     // A(ch) visible; prev readers done
    // B-fragments: global->VGPR, 1KB coalesced per (wave, ni)
    const ushort_t* wpc = wp + (size_t)ch * (G*512);
    short8 bfr[NF];
    #pragma unroll
    for (int ni = 0; ni < NF; ++ni)
      bfr[ni] = *reinterpret_cast<const short8*>(wpc + ni*512);
    short8 af[MF];
    const char* Ab = (const char*)A_lds[B];
    #pragma unroll
    for (int mi = 0; mi < MF; ++mi)
      af[mi] = *reinterpret_cast<const short8*>(Ab + aoff[mi]);
    if (prep) buildA(IC<B^1>{}, ch + 1);   // VALU fills the load shadow
    #pragma unroll
    for (int mi = 0; mi < MF; ++mi)
      #pragma unroll
      for (int ni = 0; ni < NF; ++ni)
        acc[mi][ni] = __builtin_amdgcn_mfma_f32_16x16x32_bf16(
            af[mi], bfr[ni], acc[mi][ni], 0, 0, 0);
  };

  __syncthreads();                       // halo(0) visible
  buildA(IC<0>{}, 0);

  for (int ch2 = 0; ch2 < NCH; ch2 += 2){
    body(IC<0>{}, ch2, true);
    const int nxt = ch2 + 2;
    if ((nxt < NCC) && ((nxt & 15) == 0)){ __syncthreads(); stage(nxt >> 4); }
    body(IC<1>{}, ch2 + 1, nxt < NCH);
  }

  // epilogue: + biases (+ residual), store bf16
  float bias[NF];
  #pragma unroll
  for (int ni = 0; ni < NF; ++ni){
    const int d = Nbase + ni*16 + lr;
    bias[ni] = cb[d] + db[d];
  }
  #pragma unroll
  for (int mi = 0; mi < MF; ++mi){
    #pragma unroll
    for (int r = 0; r < 4; ++r){
      const int row = mi*16 + lg*4 + r;
      const int n = ((i0 + (row >> 5)) << 8) + j0 + (row & 31);
      #pragma unroll
      for (int ni = 0; ni < NF; ++ni){
        const int d = Nbase + ni*16 + lr;
        float v = acc[mi][ni][r] + bias[ni];
        if (RESID) v += bf2f(fin[(size_t)n*Cin + d]);
        fout[(size_t)n*Cout + d] = f2bf(v);
      }
    }
  }
}

// ---------------- layer 4 (Cout=1): y[g][m] = relu(f3[m]) . Wy[g] ----------------
__global__ __launch_bounds__(256) void layer4a_kernel(
    const ushort_t* __restrict__ f3, const float* __restrict__ cw4,
    const float* __restrict__ dw4, float* __restrict__ y){
  __shared__ float Wy[17*256];
  __shared__ float red[4*1088];
  const int tid = threadIdx.x;
  for (int idx = tid; idx < 4096; idx += 256) Wy[idx] = cw4[idx];
  Wy[4096 + tid] = dw4[tid];
  __syncthreads();
  const int m = tid & 63, q = tid >> 6;
  const int n = blockIdx.x * 64 + m;
  const float4* Wy4 = reinterpret_cast<const float4*>(Wy);
  float acc[17];
  #pragma unroll
  for (int g = 0; g < 17; ++g) acc[g] = 0.0f;
  const uint4* frow = reinterpret_cast<const uint4*>(f3 + (size_t)n*256 + q*64);
  #pragma unroll
  for (int it = 0; it < 8; ++it){
    uint4 hv = frow[it];
    const uint_t* up = (const uint_t*)&hv;
    float f[8];
    #pragma unroll
    for (int w = 0; w < 4; ++w){
      uint_t u = up[w];
      f[2*w+0] = (u & 0x00008000u) ? 0.0f : __uint_as_float(u << 16);
      f[2*w+1] = (u & 0x80000000u) ? 0.0f : __uint_as_float(u & 0xFFFF0000u);
    }
    const int i4 = q*16 + it*2;
    #pragma unroll
    for (int g = 0; g < 17; ++g){
      float4 w0 = Wy4[g*64 + i4];
      float4 w1 = Wy4[g*64 + i4 + 1];
      acc[g] += w0.x*f[0] + w0.y*f[1] + w0.z*f[2] + w0.w*f[3]
              + w1.x*f[4] + w1.y*f[5] + w1.z*f[6] + w1.w*f[7];
    }
  }
  #pragma unroll
  for (int g = 0; g < 17; ++g) red[q*1088 + m*17 + g] = acc[g];
  __syncthreads();
  for (int idx = tid; idx < 1088; idx += 256){
    const int g = idx >> 6, mm = idx & 63;
    float s = red[0*1088 + mm*17 + g] + red[1*1088 + mm*17 + g]
            + red[2*1088 + mm*17 + g] + red[3*1088 + mm*17 + g];
    y[g*65536 + blockIdx.x*64 + mm] = s;
  }
}

__global__ __launch_bounds__(256) void layer4b_kernel(
    const float4* __restrict__ wgeo, const float* __restrict__ y,
    const float* __restrict__ cb4, const float* __restrict__ db4,
    float* __restrict__ out){
  const int n = blockIdx.x * 256 + threadIdx.x;
  const int i = n >> 8, j = n & 255;
  float acc = cb4[0] + db4[0] + y[16*65536 + n];
  #pragma unroll
  for (int k = 0; k < 9; ++k){
    const int di = k/3 - 1, dj = k - (k/3)*3 - 1;
    const int mi = min(max(i+di,0),255), mj = min(max(j+dj,0),255);
    const int m = (mi << 8) | mj;
    float4 geo = wgeo[n*9 + k];
    float wx[4], wy[4];
    #pragma unroll
    for (int a = 0; a < 4; ++a){
      wx[a] = fmaxf(1.0f - fabsf(geo.y - (float)a), 0.0f);
      wy[a] = fmaxf(1.0f - fabsf(geo.z - (float)a), 0.0f);
    }
    float s = 0.0f;
    #pragma unroll
    for (int ix = 0; ix < 4; ++ix){
      float sy = 0.0f;
      #pragma unroll
      for (int iy = 0; iy < 4; ++iy) sy += wy[iy] * y[(ix*4 + iy)*65536 + m];
      s += wx[ix] * sy;
    }
    acc += geo.x * s;
  }
  out[n] = tanhf(acc) * 0.8f + 1.0f;   // output f32
}

// ---------------- host launcher ----------------
extern "C" void kernel_launch(void* const* d_in, const int* in_sizes, int n_in,
                              void* d_out, int out_size, void* d_ws, size_t ws_size,
                              hipStream_t stream){
  const float* pos = (const float*)d_in[0];
  const float* vel = (const float*)d_in[1];
  const float* bng = (const float*)d_in[4];
  const float* bnb = (const float*)d_in[5];
  const bool dict = (in_sizes[8] == 96);
  const float *cwp[5], *cbp[5], *dwp[5], *dbp[5];
  for (int l = 0; l < 5; ++l){
    if (dict){
      cwp[l] = (const float*)d_in[6 + 4*l]; cbp[l] = (const float*)d_in[7 + 4*l];
      dwp[l] = (const float*)d_in[8 + 4*l]; dbp[l] = (const float*)d_in[9 + 4*l];
    } else {
      cwp[l] = (const float*)d_in[6 + 2*l];  cbp[l] = (const float*)d_in[7 + 2*l];
      dwp[l] = (const float*)d_in[16 + 2*l]; dbp[l] = (const float*)d_in[17 + 2*l];
    }
  }
  char* wsb = (char*)d_ws;
  float*    part  = (float*)   (wsb + 0);
  float*    stats = (float*)   (wsb + 4096);
  float4*   fin   = (float4*)  (wsb + 8192);
  float4*   wgeo  = (float4*)  (wsb + 1056768);
  ushort_t* Wt1   = (ushort_t*)(wsb + 10493952);
  ushort_t* Wt2   = (ushort_t*)(wsb + 10633216);
  ushort_t* Wt3   = (ushort_t*)(wsb + 10911744);
  ushort_t* f0    = (ushort_t*)(wsb + 12025856);
  ushort_t* f1    = (ushort_t*)(wsb + 20414464);
  ushort_t* f2    = (ushort_t*)(wsb + 28803072);
  ushort_t* f3    = (ushort_t*)(wsb + 45580288);
  float*    y     = (float*)   (wsb + 12025856);   // overlays f0 (dead by layer4)
  float*    outp  = (float*)d_out;

  hipLaunchKernelGGL(bn_partial, dim3(256), dim3(256), 0, stream, (const float2*)vel, part);
  hipLaunchKernelGGL(bn_final, dim3(1), dim3(256), 0, stream, part, bng, bnb, stats);
  hipLaunchKernelGGL(feats_kernel, dim3(256), dim3(256), 0, stream, (const float2*)vel, stats, fin);
  hipLaunchKernelGGL(geo_kernel, dim3(2304), dim3(256), 0, stream, (const float2*)pos, wgeo);
  hipLaunchKernelGGL((wprep<64,64>),   dim3(34),  dim3(256), 0, stream, cwp[1], dwp[1], Wt1);
  hipLaunchKernelGGL((wprep<64,128>),  dim3(68),  dim3(256), 0, stream, cwp[2], dwp[2], Wt2);
  hipLaunchKernelGGL((wprep<128,256>), dim3(272), dim3(256), 0, stream, cwp[3], dwp[3], Wt3);
  hipLaunchKernelGGL(layer0_kernel, dim3(2048), dim3(256), 0, stream,
                     fin, wgeo, cwp[0], cbp[0], dwp[0], dbp[0], f0);
  hipLaunchKernelGGL((conv_mfma<64,64,true>),   dim3(1024), dim3(256), 0, stream,
                     f0, wgeo, Wt1, cbp[1], dbp[1], f1);
  hipLaunchKernelGGL((conv_mfma<64,128,false>), dim3(1024), dim3(256), 0, stream,
                     f1, wgeo, Wt2, cbp[2], dbp[2], f2);
  hipLaunchKernelGGL((conv_mfma<128,256,false>),dim3(1024), dim3(256), 0, stream,
                     f2, wgeo, Wt3, cbp[3], dbp[3], f3);
  hipLaunchKernelGGL(layer4a_kernel, dim3(1024), dim3(256), 0, stream, f3, cwp[4], dwp[4], y);
  hipLaunchKernelGGL(layer4b_kernel, dim3(256), dim3(256), 0, stream, wgeo, y, cbp[4], dbp[4], outp);
}

// Round 12
// 243.124 us; speedup vs baseline: 1.5032x; 1.0243x over previous
//
#include <hip/hip_runtime.h>
#include <hip/hip_bf16.h>
#include <cstdint>

// ParaNet_Point round-12: dual-FP32 A-build.
// r11 counters: conv3 VALUBusy 54% vs MfmaUtil 28% -> A-build scalar-FMA chain
// is the binding pipe. Change (single, rest frozen from r11):
//  - halo stores relu'd f32 channel PAIRS (f32x2, ds_read_b64 -> {lo,hi})
//  - A-build: 36 v_pk_fma_f32 (op_sel broadcasts value half; taps stay f32x2)
//    replaces 72 scalar FMA + 18 unpacks -> per-chunk VALU ~94 -> ~45 inst.
// Numerics FMA-equivalent -> absmax must remain exactly 0.0078125.

#define GRIDW 256
#define NPTS  65536
#define RADI  0.0125f
#define EPSF  1e-12f

typedef unsigned short ushort_t;
typedef unsigned int   uint_t;
typedef __attribute__((ext_vector_type(8))) short short8;   // 8 bf16 = 4 VGPR
typedef __attribute__((ext_vector_type(4))) float f32x4;
typedef __attribute__((ext_vector_type(2))) float f32x2;

template<int N> struct IC { static constexpr int v = N; };

__device__ __forceinline__ float bf2f(ushort_t h){
  union { uint_t u; float f; } c; c.u = ((uint_t)h) << 16; return c.f;
}
__device__ __forceinline__ ushort_t f2bf(float f){
  union { float f; uint_t u; } c; c.f = f;
  uint_t u = c.u;
  u += 0x7fffu + ((u >> 16) & 1u);   // round-to-nearest-even
  return (ushort_t)(u >> 16);
}
__device__ __forceinline__ uint_t cvtpk(float a, float b){   // {bf16(b)<<16 | bf16(a)}
  uint_t r; asm("v_cvt_pk_bf16_f32 %0, %1, %2" : "=v"(r) : "v"(a), "v"(b)); return r;
}
// dual-f32 fma, value-low broadcast: d{lo,hi} += t{lo,hi} * v.lo
__device__ __forceinline__ void pkfma_lo(f32x2& d, f32x2 t, f32x2 v){
  asm("v_pk_fma_f32 %0, %1, %2, %0 op_sel:[0,0,0] op_sel_hi:[1,0,1]"
      : "+v"(d) : "v"(t), "v"(v));
}
// dual-f32 fma, value-high broadcast: d{lo,hi} += t{lo,hi} * v.hi
__device__ __forceinline__ void pkfma_hi(f32x2& d, f32x2 t, f32x2 v){
  asm("v_pk_fma_f32 %0, %1, %2, %0 op_sel:[0,1,0] op_sel_hi:[1,1,1]"
      : "+v"(d) : "v"(t), "v"(v));
}
// swizzled byte offset into 64B-row LDS tile (row-dep XOR of 16B slot)
__device__ __forceinline__ int swz(int row, int byteoff){
  return row*64 + ((((byteoff >> 4) ^ ((row >> 1) & 3)) & 3) << 4) + (byteoff & 15);
}

// ---------------- BatchNorm statistics ----------------
__global__ __launch_bounds__(256) void bn_partial(const float2* __restrict__ vel,
                                                  float* __restrict__ part){
  __shared__ float s[256][4];
  const int t = threadIdx.x;
  const int id = blockIdx.x * 256 + t;
  float2 v = vel[id];
  s[t][0] = v.x; s[t][1] = v.y; s[t][2] = v.x * v.x; s[t][3] = v.y * v.y;
  __syncthreads();
  for (int off = 128; off > 0; off >>= 1){
    if (t < off){
      s[t][0] += s[t+off][0]; s[t][1] += s[t+off][1];
      s[t][2] += s[t+off][2]; s[t][3] += s[t+off][3];
    }
    __syncthreads();
  }
  if (t == 0){
    part[blockIdx.x*4+0] = s[0][0]; part[blockIdx.x*4+1] = s[0][1];
    part[blockIdx.x*4+2] = s[0][2]; part[blockIdx.x*4+3] = s[0][3];
  }
}

__global__ __launch_bounds__(256) void bn_final(const float* __restrict__ part,
                                                const float* __restrict__ gamma,
                                                const float* __restrict__ beta,
                                                float* __restrict__ stats){
  __shared__ float s[256][4];
  const int t = threadIdx.x;
  const float4 p = reinterpret_cast<const float4*>(part)[t];
  s[t][0] = p.x; s[t][1] = p.y; s[t][2] = p.z; s[t][3] = p.w;
  __syncthreads();
  for (int off = 128; off > 0; off >>= 1){
    if (t < off){
      s[t][0] += s[t+off][0]; s[t][1] += s[t+off][1];
      s[t][2] += s[t+off][2]; s[t][3] += s[t+off][3];
    }
    __syncthreads();
  }
  if (t == 0){
    const float invN = 1.0f / 65536.0f;
    float m0 = s[0][0]*invN, m1 = s[0][1]*invN;
    float var0 = s[0][2]*invN - m0*m0;
    float var1 = s[0][3]*invN - m1*m1;
    float A0 = gamma[0] * rsqrtf(var0 + 1e-5f);
    float A1 = gamma[1] * rsqrtf(var1 + 1e-5f);
    stats[0] = A0; stats[1] = beta[0] - A0*m0;
    stats[2] = A1; stats[3] = beta[1] - A1*m1;
    stats[4] = beta[2];   // z-col of vel3 is identically 0
  }
}

__global__ __launch_bounds__(256) void feats_kernel(const float2* __restrict__ vel,
                                                    const float* __restrict__ stats,
                                                    float4* __restrict__ fin){
  const int id = blockIdx.x * 256 + threadIdx.x;
  float2 v = vel[id];
  float A0 = stats[0], B0 = stats[1], A1 = stats[2], B1 = stats[3], C2 = stats[4];
  fin[id] = make_float4(A0*v.x + B0, A1*v.y + B1, C2, 0.0f);
}

// ---------------- filter geometry: (win, gx, gy) per (n,k) ----------------
__global__ __launch_bounds__(256) void geo_kernel(const float2* __restrict__ pos,
                                                  float4* __restrict__ wgeo){
  const int id = blockIdx.x * 256 + threadIdx.x;   // < N*9 exactly
  const int n = id / 9;
  const int k = id - n * 9;
  const int i = n >> 8, j = n & 255;
  const int di = k / 3 - 1, dj = k - (k/3)*3 - 1;
  const int ni = i + di, nj = j + dj;
  const bool valid = (ni >= 0) && (ni < GRIDW) && (nj >= 0) && (nj < GRIDW);
  const int mi = min(max(ni, 0), GRIDW-1), mj = min(max(nj, 0), GRIDW-1);
  const int m = (mi << 8) | mj;
  float2 pn = pos[n], pm = pos[m];
  float x = (pm.x - pn.x) * (1.0f / RADI);
  float y = (pm.y - pn.y) * (1.0f / RADI);
  float sq = x*x + y*y;                 // z == 0 throughout
  bool nz = sq > EPSF;
  float cx = nz ? x : 0.0f;
  float cy = nz ? y : 0.0f;
  float rr = cx*cx + cy*cy;
  float r = sqrtf(fmaxf(rr, EPSF));
  float acx = fabsf(cx), acy = fabsf(cy);
  bool condx = acx >= acy;
  float dx  = (acx > 1e-9f) ? cx : 1.0f;
  float dyv = (acy > 1e-9f) ? cy : 1.0f;
  const float fop = 1.27323954473516268615f;   // 4/pi
  float sx = (cx > 0.f) ? 1.f : ((cx < 0.f) ? -1.f : 0.f);
  float sy = (cy > 0.f) ? 1.f : ((cy < 0.f) ? -1.f : 0.f);
  float u, v;
  if (condx){ u = sx * r;                    v = sx * r * fop * atanf(cy/dx); }
  else      { u = sy * r * fop * atanf(cx/dyv); v = sy * r; }
  if (rr <= EPSF){ u = 0.0f; v = 0.0f; }
  float gx = fminf(fmaxf((u + 1.0f) * 1.5f, 0.0f), 3.0f);
  float gy = fminf(fmaxf((v + 1.0f) * 1.5f, 0.0f), 3.0f);
  float pw = 1.0f - fminf(fmaxf(sq, 0.0f), 1.0f);
  float win = pw * pw * pw;
  win = (sq <= 1.0f && valid) ? win : 0.0f;
  wgeo[id] = make_float4(win, gx, gy, 0.0f);
}

// -- W pre-pack into MFMA B-fragment order --------------------------------
// Wfrag[((ch*G + grp)*64 + l)*8 + e] = bf16(W[kk = ch*32 + (l>>4)*8 + e]
//                                          [d  = grp*16 + (l&15)])
template<int Cin, int Cout>
__global__ __launch_bounds__(256) void wprep(const float* __restrict__ cw,
                                             const float* __restrict__ dw,
                                             ushort_t* __restrict__ Wf){
  constexpr int G = Cout/16;
  const int id = blockIdx.x*256 + threadIdx.x;     // grid sized exactly
  const int ch = id / (G*64);
  const int r  = id - ch*G*64;
  const int grp = r >> 6, l = r & 63;
  const int d  = grp*16 + (l & 15);
  const int kb = ch*32 + (l >> 4)*8;
  ushort_t o[8];
  #pragma unroll
  for (int e = 0; e < 8; ++e){
    const int kk = kb + e;
    float v;
    if (kk < 16*Cin){ int c = kk >> 4, g = kk & 15; v = cw[(size_t)(g*Cin + c)*Cout + d]; }
    else v = dw[(size_t)(kk - 16*Cin)*Cout + d];
    o[e] = f2bf(v);
  }
  *reinterpret_cast<uint4*>(Wf + (size_t)id*8) = *reinterpret_cast<uint4*>(o);
}

// ---------------- layer 0: Cin=3 direct (VALU, small) ----------------
__global__ __launch_bounds__(256) void layer0_kernel(
    const float4* __restrict__ fin, const float4* __restrict__ wgeo,
    const float* __restrict__ cw, const float* __restrict__ cb,
    const float* __restrict__ dw, const float* __restrict__ db,
    ushort_t* __restrict__ f0){
  __shared__ float Wc[48*32];
  __shared__ float Wd[96];
  __shared__ float Bs[64];
  const int tid = threadIdx.x;
  for (int idx = tid; idx < 1536; idx += 256) Wc[idx] = cw[idx];
  if (tid < 96) Wd[tid] = dw[tid];
  if (tid < 32){ Bs[tid] = cb[tid]; Bs[32+tid] = db[tid]; }
  __syncthreads();
  const int p = tid >> 3, q = tid & 7;
  const int n = blockIdx.x * 32 + p;
  const int i = n >> 8, j = n & 255;
  float A[48];
  #pragma unroll
  for (int a = 0; a < 48; ++a) A[a] = 0.0f;
  const float4 fc = fin[n];
  #pragma unroll
  for (int k = 0; k < 9; ++k){
    const int di = k/3 - 1, dj = k - (k/3)*3 - 1;
    const int mi = min(max(i+di,0),255), mj = min(max(j+dj,0),255);
    const int m = (mi << 8) | mj;
    float4 geo = wgeo[n*9 + k];
    float4 fm = fin[m];
    float wx[4], wy[4];
    #pragma unroll
    for (int a = 0; a < 4; ++a){
      wx[a] = fmaxf(1.0f - fabsf(geo.y - (float)a), 0.0f);
      wy[a] = fmaxf(1.0f - fabsf(geo.z - (float)a), 0.0f);
    }
    #pragma unroll
    for (int ix = 0; ix < 4; ++ix)
      #pragma unroll
      for (int iy = 0; iy < 4; ++iy){
        float w = geo.x * wx[ix] * wy[iy];
        int g = ix*4 + iy;
        A[g*3+0] += w * fm.x; A[g*3+1] += w * fm.y; A[g*3+2] += w * fm.z;
      }
  }
  if (q < 4){
    #pragma unroll
    for (int jj = 0; jj < 8; ++jj){
      int d = q*8 + jj;
      float acc = Bs[d];
      #pragma unroll
      for (int a = 0; a < 48; ++a) acc += A[a] * Wc[a*32 + d];
      f0[n*64 + d] = f2bf(acc);
    }
  } else {
    #pragma unroll
    for (int jj = 0; jj < 8; ++jj){
      int d2 = (q-4)*8 + jj;
      float acc = Bs[32+d2] + fc.x*Wd[0*32+d2] + fc.y*Wd[1*32+d2] + fc.z*Wd[2*32+d2];
      f0[n*64 + 32 + d2] = f2bf(acc);
    }
  }
}

// ---- MFMA conv+dense layers: A in LDS (dbuf), W global->VGPR fragments ----
template<int Cin, int Cout, bool RESID>
__global__ __launch_bounds__(256) void conv_mfma(
    const ushort_t* __restrict__ fin, const float4* __restrict__ wgeo,
    const ushort_t* __restrict__ Wf,
    const float* __restrict__ cb, const float* __restrict__ db,
    ushort_t* __restrict__ fout){
  constexpr int K   = 17*Cin;
  constexpr int NCC = Cin/2;            // conv chunks
  constexpr int NCH = K/32;             // total chunks (even)
  constexpr int HSTR = 137;             // halo row stride in f32x2 units
  constexpr int G   = Cout/16;          // 16-col groups per chunk
  constexpr int MF  = 4;                // every wave covers all 64 rows
  constexpr int NF  = Cout/64;          // col groups per wave

  __shared__ f32x2 halo64[16*HSTR];                   // 17536 B, relu'd pairs
  __shared__ __align__(16) ushort_t A_lds[2][64*32];  // 2 x 4 KB, swizzled

  const int tid = threadIdx.x;
  const int i0 = (blockIdx.x >> 3) * 2;
  const int j0 = (blockIdx.x & 7) * 32;

  auto stage = [&](int ph){
    for (int idx = tid; idx < 544; idx += 256){
      const int loc = idx >> 2, c8l = idx & 3;
      const int r = loc / 34, col = loc - r*34;
      const int gi = min(max(i0 - 1 + r, 0), 255);
      const int gj = min(max(j0 - 1 + col, 0), 255);
      const int mm = (gi << 8) | gj;
      uint4 v = *reinterpret_cast<const uint4*>(fin + (size_t)mm*Cin + ph*32 + c8l*8);
      const uint_t* vp = (const uint_t*)&v;
      #pragma unroll
      for (int q = 0; q < 4; ++q){
        uint_t u = vp[q];
        f32x2 f;
        f.x = fmaxf(__uint_as_float(u << 16), 0.0f);
        f.y = fmaxf(__uint_as_float(u & 0xFFFF0000u), 0.0f);
        halo64[(c8l*4 + q)*HSTR + loc] = f;
      }
    }
  };

  const int m  = tid & 63;              // local point == lane
  const int gq = tid >> 6;              // g-quarter AND wave id
  const int g0 = gq * 4;
  const int n_m = ((i0 + (m >> 5)) << 8) + j0 + (m & 31);
  const int lane = m;
  const int lr = lane & 15, lg = lane >> 4;
  const int ctr = (1 + (m >> 5))*34 + 1 + (m & 31);

  stage(0);
  // taps as f32x2 pairs {g0,g1},{g2,g3} per k (pk_fma operands, no copies)
  f32x2 tap2[9][2];
  #pragma unroll
  for (int k = 0; k < 9; ++k){
    float4 geo = wgeo[(size_t)n_m*9 + k];
    float wxg = fmaxf(1.0f - fabsf(geo.y - (float)gq), 0.0f);
    float s = geo.x * wxg;
    tap2[k][0].x = s * fmaxf(1.0f - fabsf(geo.z - 0.0f), 0.0f);
    tap2[k][0].y = s * fmaxf(1.0f - fabsf(geo.z - 1.0f), 0.0f);
    tap2[k][1].x = s * fmaxf(1.0f - fabsf(geo.z - 2.0f), 0.0f);
    tap2[k][1].y = s * fmaxf(1.0f - fabsf(geo.z - 3.0f), 0.0f);
  }

  const int Nbase = gq * (NF*16);       // wave's unique column block

  int aoff[MF];
  #pragma unroll
  for (int mi = 0; mi < MF; ++mi) aoff[mi] = swz(mi*16 + lr, lg*16);
  const int s0 = swz(m, 2*g0);
  const int s1 = swz(m, 32 + 2*g0);
  const int sd = swz(m, gq*16);

  // wave's W-fragment base: (chunk 0, grp = gq*NF + ni), lane slot
  const ushort_t* wp = Wf + (size_t)(gq*NF)*512 + lane*8;

  f32x4 acc[MF][NF];
  #pragma unroll
  for (int a = 0; a < MF; ++a)
    #pragma unroll
    for (int b = 0; b < NF; ++b) acc[a][b] = (f32x4){0.f,0.f,0.f,0.f};

  auto buildA = [&](auto BC, int ch){
    constexpr int B = decltype(BC)::v;
    char* Ab = (char*)A_lds[B];
    if (ch < NCC){
      const f32x2* hb = &halo64[(ch & 15)*HSTR + ctr - 35];
      f32x2 a01 = {0.f,0.f}, a23 = {0.f,0.f};   // lo channel, g{0,1},{2,3}
      f32x2 b01 = {0.f,0.f}, b23 = {0.f,0.f};   // hi channel
      #pragma unroll
      for (int kr = 0; kr < 3; ++kr)
        #pragma unroll
        for (int kc = 0; kc < 3; ++kc){
          const f32x2 val = hb[kr*34 + kc];
          const int k = kr*3 + kc;
          pkfma_lo(a01, tap2[k][0], val);
          pkfma_lo(a23, tap2[k][1], val);
          pkfma_hi(b01, tap2[k][0], val);
          pkfma_hi(b23, tap2[k][1], val);
        }
      uint2 plo, phi;
      plo.x = cvtpk(a01.x, a01.y); plo.y = cvtpk(a23.x, a23.y);
      phi.x = cvtpk(b01.x, b01.y); phi.y = cvtpk(b23.x, b23.y);
      *reinterpret_cast<uint2*>(Ab + s0) = plo;
      *reinterpret_cast<uint2*>(Ab + s1) = phi;
    } else {
      const int cd0 = (ch - NCC)*32 + gq*8;   // 8 dense channels per thread
      uint4 u = *reinterpret_cast<const uint4*>(fin + (size_t)n_m*Cin + cd0);
      uint_t* up = (uint_t*)&u;
      #pragma unroll
      for (int q = 0; q < 4; ++q){
        uint_t w = up[q];
        uint_t lo = (w & 0x00008000u) ? 0u : (w & 0x0000FFFFu);
        uint_t hi = (w & 0x80000000u) ? 0u : (w & 0xFFFF0000u);
        up[q] = hi | lo;
      }
      *reinterpret_cast<uint4*>(Ab + sd) = u;
    }
  };

  auto body = [&](auto BC, int ch, bool prep){
    constexpr int B = decltype(BC)::v;
    __syncthreads();                     // A(ch) visible; prev readers done
    // B-fragments: global->VGPR, 1KB coalesced per (wave, ni)
    const ushort_t* wpc = wp + (size_t)ch * (G*512);
    short8 bfr[NF];
    #pragma unroll
    for (int ni = 0; ni < NF; ++ni)
      bfr[ni] = *reinterpret_cast<const short8*>(wpc + ni*512);
    short8 af[MF];
    const char* Ab = (const char*)A_lds[B];
    #pragma unroll
    for (int mi = 0; mi < MF; ++mi)
      af[mi] = *reinterpret_cast<const short8*>(Ab + aoff[mi]);
    if (prep) buildA(IC<B^1>{}, ch + 1);   // VALU fills the load shadow
    #pragma unroll
    for (int mi = 0; mi < MF; ++mi)
      #pragma unroll
      for (int ni = 0; ni < NF; ++ni)
        acc[mi][ni] = __builtin_amdgcn_mfma_f32_16x16x32_bf16(
            af[mi], bfr[ni], acc[mi][ni], 0, 0, 0);
  };

  __syncthreads();                       // halo(0) visible
  buildA(IC<0>{}, 0);

  for (int ch2 = 0; ch2 < NCH; ch2 += 2){
    body(IC<0>{}, ch2, true);
    const int nxt = ch2 + 2;
    if ((nxt < NCC) && ((nxt & 15) == 0)){ __syncthreads(); stage(nxt >> 4); }
    body(IC<1>{}, ch2 + 1, nxt < NCH);
  }

  // epilogue: + biases (+ residual), store bf16
  float bias[NF];
  #pragma unroll
  for (int ni = 0; ni < NF; ++ni){
    const int d = Nbase + ni*16 + lr;
    bias[ni] = cb[d] + db[d];
  }
  #pragma unroll
  for (int mi = 0; mi < MF; ++mi){
    #pragma unroll
    for (int r = 0; r < 4; ++r){
      const int row = mi*16 + lg*4 + r;
      const int n = ((i0 + (row >> 5)) << 8) + j0 + (row & 31);
      #pragma unroll
      for (int ni = 0; ni < NF; ++ni){
        const int d = Nbase + ni*16 + lr;
        float v = acc[mi][ni][r] + bias[ni];
        if (RESID) v += bf2f(fin[(size_t)n*Cin + d]);
        fout[(size_t)n*Cout + d] = f2bf(v);
      }
    }
  }
}

// ---------------- layer 4 (Cout=1): y[g][m] = relu(f3[m]) . Wy[g] ----------------
__global__ __launch_bounds__(256) void layer4a_kernel(
    const ushort_t* __restrict__ f3, const float* __restrict__ cw4,
    const float* __restrict__ dw4, float* __restrict__ y){
  __shared__ float Wy[17*256];
  __shared__ float red[4*1088];
  const int tid = threadIdx.x;
  for (int idx = tid; idx < 4096; idx += 256) Wy[idx] = cw4[idx];
  Wy[4096 + tid] = dw4[tid];
  __syncthreads();
  const int m = tid & 63, q = tid >> 6;
  const int n = blockIdx.x * 64 + m;
  const float4* Wy4 = reinterpret_cast<const float4*>(Wy);
  float acc[17];
  #pragma unroll
  for (int g = 0; g < 17; ++g) acc[g] = 0.0f;
  const uint4* frow = reinterpret_cast<const uint4*>(f3 + (size_t)n*256 + q*64);
  #pragma unroll
  for (int it = 0; it < 8; ++it){
    uint4 hv = frow[it];
    const uint_t* up = (const uint_t*)&hv;
    float f[8];
    #pragma unroll
    for (int w = 0; w < 4; ++w){
      uint_t u = up[w];
      f[2*w+0] = (u & 0x00008000u) ? 0.0f : __uint_as_float(u << 16);
      f[2*w+1] = (u & 0x80000000u) ? 0.0f : __uint_as_float(u & 0xFFFF0000u);
    }
    const int i4 = q*16 + it*2;
    #pragma unroll
    for (int g = 0; g < 17; ++g){
      float4 w0 = Wy4[g*64 + i4];
      float4 w1 = Wy4[g*64 + i4 + 1];
      acc[g] += w0.x*f[0] + w0.y*f[1] + w0.z*f[2] + w0.w*f[3]
              + w1.x*f[4] + w1.y*f[5] + w1.z*f[6] + w1.w*f[7];
    }
  }
  #pragma unroll
  for (int g = 0; g < 17; ++g) red[q*1088 + m*17 + g] = acc[g];
  __syncthreads();
  for (int idx = tid; idx < 1088; idx += 256){
    const int g = idx >> 6, mm = idx & 63;
    float s = red[0*1088 + mm*17 + g] + red[1*1088 + mm*17 + g]
            + red[2*1088 + mm*17 + g] + red[3*1088 + mm*17 + g];
    y[g*65536 + blockIdx.x*64 + mm] = s;
  }
}

__global__ __launch_bounds__(256) void layer4b_kernel(
    const float4* __restrict__ wgeo, const float* __restrict__ y,
    const float* __restrict__ cb4, const float* __restrict__ db4,
    float* __restrict__ out){
  const int n = blockIdx.x * 256 + threadIdx.x;
  const int i = n >> 8, j = n & 255;
  float acc = cb4[0] + db4[0] + y[16*65536 + n];
  #pragma unroll
  for (int k = 0; k < 9; ++k){
    const int di = k/3 - 1, dj = k - (k/3)*3 - 1;
    const int mi = min(max(i+di,0),255), mj = min(max(j+dj,0),255);
    const int m = (mi << 8) | mj;
    float4 geo = wgeo[n*9 + k];
    float wx[4], wy[4];
    #pragma unroll
    for (int a = 0; a < 4; ++a){
      wx[a] = fmaxf(1.0f - fabsf(geo.y - (float)a), 0.0f);
      wy[a] = fmaxf(1.0f - fabsf(geo.z - (float)a), 0.0f);
    }
    float s = 0.0f;
    #pragma unroll
    for (int ix = 0; ix < 4; ++ix){
      float sy = 0.0f;
      #pragma unroll
      for (int iy = 0; iy < 4; ++iy) sy += wy[iy] * y[(ix*4 + iy)*65536 + m];
      s += wx[ix] * sy;
    }
    acc += geo.x * s;
  }
  out[n] = tanhf(acc) * 0.8f + 1.0f;   // output f32
}

// ---------------- host launcher ----------------
extern "C" void kernel_launch(void* const* d_in, const int* in_sizes, int n_in,
                              void* d_out, int out_size, void* d_ws, size_t ws_size,
                              hipStream_t stream){
  const float* pos = (const float*)d_in[0];
  const float* vel = (const float*)d_in[1];
  const float* bng = (const float*)d_in[4];
  const float* bnb = (const float*)d_in[5];
  const bool dict = (in_sizes[8] == 96);
  const float *cwp[5], *cbp[5], *dwp[5], *dbp[5];
  for (int l = 0; l < 5; ++l){
    if (dict){
      cwp[l] = (const float*)d_in[6 + 4*l]; cbp[l] = (const float*)d_in[7 + 4*l];
      dwp[l] = (const float*)d_in[8 + 4*l]; dbp[l] = (const float*)d_in[9 + 4*l];
    } else {
      cwp[l] = (const float*)d_in[6 + 2*l];  cbp[l] = (const float*)d_in[7 + 2*l];
      dwp[l] = (const float*)d_in[16 + 2*l]; dbp[l] = (const float*)d_in[17 + 2*l];
    }
  }
  char* wsb = (char*)d_ws;
  float*    part  = (float*)   (wsb + 0);
  float*    stats = (float*)   (wsb + 4096);
  float4*   fin   = (float4*)  (wsb + 8192);
  float4*   wgeo  = (float4*)  (wsb + 1056768);
  ushort_t* Wt1   = (ushort_t*)(wsb + 10493952);
  ushort_t* Wt2   = (ushort_t*)(wsb + 10633216);
  ushort_t* Wt3   = (ushort_t*)(wsb + 10911744);
  ushort_t* f0    = (ushort_t*)(wsb + 12025856);
  ushort_t* f1    = (ushort_t*)(wsb + 20414464);
  ushort_t* f2    = (ushort_t*)(wsb + 28803072);
  ushort_t* f3    = (ushort_t*)(wsb + 45580288);
  float*    y     = (float*)   (wsb + 12025856);   // overlays f0 (dead by layer4)
  float*    outp  = (float*)d_out;

  hipLaunchKernelGGL(bn_partial, dim3(256), dim3(256), 0, stream, (const float2*)vel, part);
  hipLaunchKernelGGL(bn_final, dim3(1), dim3(256), 0, stream, part, bng, bnb, stats);
  hipLaunchKernelGGL(feats_kernel, dim3(256), dim3(256), 0, stream, (const float2*)vel, stats, fin);
  hipLaunchKernelGGL(geo_kernel, dim3(2304), dim3(256), 0, stream, (const float2*)pos, wgeo);
  hipLaunchKernelGGL((wprep<64,64>),   dim3(34),  dim3(256), 0, stream, cwp[1], dwp[1], Wt1);
  hipLaunchKernelGGL((wprep<64,128>),  dim3(68),  dim3(256), 0, stream, cwp[2], dwp[2], Wt2);
  hipLaunchKernelGGL((wprep<128,256>), dim3(272), dim3(256), 0, stream, cwp[3], dwp[3], Wt3);
  hipLaunchKernelGGL(layer0_kernel, dim3(2048), dim3(256), 0, stream,
                     fin, wgeo, cwp[0], cbp[0], dwp[0], dbp[0], f0);
  hipLaunchKernelGGL((conv_mfma<64,64,true>),   dim3(1024), dim3(256), 0, stream,
                     f0, wgeo, Wt1, cbp[1], dbp[1], f1);
  hipLaunchKernelGGL((conv_mfma<64,128,false>), dim3(1024), dim3(256), 0, stream,
                     f1, wgeo, Wt2, cbp[2], dbp[2], f2);
  hipLaunchKernelGGL((conv_mfma<128,256,false>),dim3(1024), dim3(256), 0, stream,
                     f2, wgeo, Wt3, cbp[3], dbp[3], f3);
  hipLaunchKernelGGL(layer4a_kernel, dim3(1024), dim3(256), 0, stream, f3, cwp[4], dwp[4], y);
  hipLaunchKernelGGL(layer4b_kernel, dim3(256), dim3(256), 0, stream, wgeo, y, cbp[4], dbp[4], outp);
}